// Round 2
// baseline (98.386 us; speedup 1.0000x reference)
//
#include <hip/hip_runtime.h>
#include <math.h>

// RotatedGaussianAssigner — MI355X (gfx950)
// B=8 batches, NGT=64 gt boxes, L=21824 anchors (strides 8/16/32/64/128), C=15.
// Output (flat float32): labels [B*L] | boxes [B*L*5] | scores [B*L*15]
//
// Structure: phase-1 precomputes per-GT params into d_ws (7 float4 per GT);
// phase-2 (one thread per anchor) reads them with wave-uniform addresses so
// the compiler promotes them to s_load (SMEM pipe, SGPR operands) — no LDS,
// no __syncthreads in the hot kernel.

#define NUMC 15
#define NGT  64
#define LTOT 21824
#define NB   8
#define EPSV 1e-9f
#define SCORE_THR 0.23f

// ws layout: float4 W[b][n][7]
//  j0: {cx, cy, ax, ay}
//  j1: {vabx, vaby, vadx, vady}
//  j2: {nab2, nad2, inv_dxden, inv_dyden}
//  j3: {x1, y1, x2, y2}
//  j4: {irp, pm1, labelf, 0}       irp = inv_refden*pad, pm1 = pad-1
//  j5: {w, h, ang, det2}           (epilogue: assigned box + probiou)
//  j6: {ga2, gb2, gc2, 0}          (epilogue: gt gaussian covariance)

__global__ __launch_bounds__(512) void rga_prep(
    const float* __restrict__ gt_boxes,    // [B,NGT,5]
    const int*   __restrict__ gt_labels,   // [B,NGT]
    const float* __restrict__ pad_gt_mask, // [B,NGT]
    float4* __restrict__ W)
{
    const int t = threadIdx.x;          // t = b*64 + n
    if (t >= NB * NGT) return;
    const float* g = gt_boxes + (size_t)t * 5;
    const float cx = g[0], cy = g[1], w = g[2], h = g[3], ang = g[4];
    const float ca = cosf(ang), sa = sinf(ang);
    const float hw = 0.5f * w, hh = 0.5f * h;
    const float ax = (-hw) * ca - (-hh) * sa + cx;
    const float ay = (-hw) * sa + (-hh) * ca + cy;
    const float bx = ( hw) * ca - (-hh) * sa + cx;
    const float by = ( hw) * sa + (-hh) * ca + cy;
    const float dx_ = (-hw) * ca - ( hh) * sa + cx;
    const float dy_ = (-hw) * sa + ( hh) * ca + cy;
    const float vabx = bx - ax, vaby = by - ay;
    const float vadx = dx_ - ax, vady = dy_ - ay;
    const float nab2 = vabx * vabx + vaby * vaby;
    const float nad2 = vadx * vadx + vady * vady;
    const float norm_ab = sqrtf(nab2 + EPSV);
    const float norm_ad = sqrtf(nad2 + EPSV);
    const float min_edge = fminf(w, h);
    const float inv_dxden = 1.0f / (norm_ab * norm_ab * norm_ab * min_edge + EPSV);
    const float inv_dyden = 1.0f / (norm_ad * norm_ad * norm_ad * min_edge + EPSV);
    const float sigma = min_edge / 12.0f;
    const float inv_refden = 1.0f / (6.2831853071795864769f * sigma + EPSV);
    const float aca = fabsf(ca), asa = fabsf(sa);
    const float ew = 0.5f * (w * aca + h * asa);
    const float eh = 0.5f * (w * asa + h * aca);
    const float w2 = w * w / 12.0f, h2 = h * h / 12.0f;
    const float ga2 = w2 * ca * ca + h2 * sa * sa;
    const float gb2 = w2 * sa * sa + h2 * ca * ca;
    const float gc2 = (w2 - h2) * ca * sa;
    const float det2 = fmaxf(ga2 * gb2 - gc2 * gc2, 0.0f);
    const float pad = pad_gt_mask[t];
    const float labelf = (float)gt_labels[t];

    float4* o = W + (size_t)t * 7;
    o[0] = make_float4(cx, cy, ax, ay);
    o[1] = make_float4(vabx, vaby, vadx, vady);
    o[2] = make_float4(nab2, nad2, inv_dxden, inv_dyden);
    o[3] = make_float4(cx - ew, cy - eh, cx + ew, cy + eh);
    o[4] = make_float4(inv_refden * pad, pad - 1.0f, labelf, 0.0f);
    o[5] = make_float4(w, h, ang, det2);
    o[6] = make_float4(ga2, gb2, gc2, 0.0f);
}

__global__ __launch_bounds__(256) void rga_main(
    const float*  __restrict__ pred_boxes,    // [B,L,5]
    const float*  __restrict__ anchor_points, // [L,2]
    const int*    __restrict__ bg_index_p,    // [1]
    const float4* __restrict__ W,             // [B,NGT,7]
    float* __restrict__ out)
{
    const int b = blockIdx.y;
    const int l = blockIdx.x * blockDim.x + threadIdx.x;
    if (l >= LTOT) return;

    const float2 p = ((const float2*)anchor_points)[l];
    const float px = p.x, py = p.y;

    // regress-range per anchor level (cumulative level boundaries)
    float low, high;
    if (l < 16384)      { low = -1.0f;   high = 64.0f;  }
    else if (l < 20480) { low = 64.0f;   high = 128.0f; }
    else if (l < 21504) { low = 128.0f;  high = 256.0f; }
    else if (l < 21760) { low = 256.0f;  high = 512.0f; }
    else                { low = 512.0f;  high = 1e8f;   }

    const float4* __restrict__ Pb = W + (size_t)b * NGT * 7;  // uniform base

    float best = -2.0f;
    int   bidx = 0;
    #pragma unroll 2
    for (int n = 0; n < NGT; ++n) {
        const float4 f0 = Pb[n * 7 + 0];   // uniform addr -> s_load
        const float4 f1 = Pb[n * 7 + 1];
        const float4 f2 = Pb[n * 7 + 2];
        const float4 f3 = Pb[n * 7 + 3];
        const float4 f4 = Pb[n * 7 + 4];
        const float ctpx = px - f0.x, ctpy = py - f0.y;
        const float dot_ab = ctpx * f1.x + ctpy * f1.y;
        const float dot_ad = ctpx * f1.z + ctpy * f1.w;
        const float delta = dot_ab * dot_ab * f2.z + dot_ad * dot_ad * f2.w;
        const float gauss = __expf(-6.0f * delta);
        const float apx = px - f0.z, apy = py - f0.w;
        const float ap_ab = apx * f1.x + apy * f1.y;
        const float ap_ad = apx * f1.z + apy * f1.w;
        const bool inside = (ap_ab >= EPSV) & (ap_ab <= f2.x) &
                            (ap_ad >= EPSV) & (ap_ad <= f2.y);
        const float ltrb = fmaxf(fmaxf(px - f3.x, py - f3.y),
                                 fmaxf(f3.z - px, f3.w - py));
        const bool ok = inside & (gauss > SCORE_THR) & (ltrb >= low) & (ltrb <= high);
        const float masked = ok ? fmaf(gauss, f4.x, f4.y) : -1.0f;
        if (masked > best) { best = masked; bidx = n; }
    }

    const int bg = bg_index_p[0];
    const bool pos = best > 0.0f;

    const float4* Wn = Pb + bidx * 7;      // divergent -> vector loads (rare path data)
    const float4 s0 = Wn[0];
    const float4 s4 = Wn[4];
    const float4 e0 = Wn[5];
    const float4 e1 = Wn[6];

    const int lbl = pos ? (int)s4.z : bg;

    const size_t idx = (size_t)b * LTOT + l;
    out[idx] = (float)lbl;

    float* outB = out + (size_t)NB * LTOT + idx * 5;
    outB[0] = pos ? s0.x : 0.0f;
    outB[1] = pos ? s0.y : 0.0f;
    outB[2] = pos ? e0.x : 0.0f;
    outB[3] = pos ? e0.y : 0.0f;
    outB[4] = pos ? e0.z : 0.0f;

    float iou = 0.0f;
    if (pos) {
        const float* pb = pred_boxes + idx * 5;
        const float pcx = pb[0], pcy = pb[1], pw = pb[2], ph = pb[3], pang = pb[4];
        const float ca = __cosf(pang), sa = __sinf(pang);
        const float w2 = pw * pw / 12.0f, h2 = ph * ph / 12.0f;
        const float a1 = w2 * ca * ca + h2 * sa * sa;
        const float b1 = w2 * sa * sa + h2 * ca * ca;
        const float c1 = (w2 - h2) * ca * sa;
        const float dx = pcx - s0.x, dy = pcy - s0.y;
        const float aa = a1 + e1.x, bb = b1 + e1.y, cc = c1 + e1.z;
        const float denom = aa * bb - cc * cc + 1e-3f;
        const float t1 = 0.25f * (aa * dy * dy + bb * dx * dx) / denom;
        const float t2 = 0.5f * (cc * (-(dx * dy))) / denom;
        const float det1 = fmaxf(a1 * b1 - c1 * c1, 0.0f);
        const float t3 = 0.5f * __logf(denom / (4.0f * __fsqrt_rn(det1 * e0.w) + 1e-3f) + 1e-3f);
        float bd = t1 + t2 + t3;
        bd = fminf(fmaxf(bd, 1e-3f), 100.0f);
        iou = 1.0f - sqrtf(1.0f - __expf(-bd) + 1e-3f);
    }

    float* outS = out + (size_t)NB * LTOT * 6 + idx * NUMC;
    #pragma unroll
    for (int c = 0; c < NUMC; ++c)
        outS[c] = (pos && c == lbl) ? iou : 0.0f;
}

extern "C" void kernel_launch(void* const* d_in, const int* in_sizes, int n_in,
                              void* d_out, int out_size, void* d_ws, size_t ws_size,
                              hipStream_t stream) {
    // inputs: 0 pred_scores (unused), 1 pred_boxes, 2 anchor_points, 3 gt_labels,
    //         4 gt_boxes, 5 pad_gt_mask, 6 bg_index, 7 stride_tensor (unused)
    const float* pred_boxes    = (const float*)d_in[1];
    const float* anchor_points = (const float*)d_in[2];
    const int*   gt_labels     = (const int*)d_in[3];
    const float* gt_boxes      = (const float*)d_in[4];
    const float* pad_gt_mask   = (const float*)d_in[5];
    const int*   bg_index_p    = (const int*)d_in[6];
    float*       out           = (float*)d_out;
    float4*      W             = (float4*)d_ws;   // 8*64*7*16 = 57344 B

    rga_prep<<<dim3(1), dim3(512), 0, stream>>>(gt_boxes, gt_labels, pad_gt_mask, W);

    dim3 grid((LTOT + 255) / 256, NB);
    rga_main<<<grid, dim3(256), 0, stream>>>(
        pred_boxes, anchor_points, bg_index_p, W, out);
}

// Round 3
// 83.454 us; speedup vs baseline: 1.1789x; 1.1789x over previous
//
#include <hip/hip_runtime.h>
#include <math.h>

// RotatedGaussianAssigner — MI355X (gfx950)
// B=8 batches, NGT=64 gt boxes, L=21824 anchors (strides 8/16/32/64/128), C=15.
// Output (flat float32): labels [B*L] | boxes [B*L*5] | scores [B*L*15]
//
// Single fused kernel. Each 256-thread block handles 256 consecutive anchors
// (always within ONE pyramid level) for one batch. Block prologue: 64 lanes
// compute per-GT params into LDS, then cull GTs whose AABB / regress-range
// cannot possibly produce a positive in this block's anchor strip (ballot +
// popcount compaction, order-preserving). Inner loop runs only survivors.

#define NUMC 15
#define NGT  64
#define LTOT 21824
#define NB   8
#define EPSV 1e-9f
#define SCORE_THR 0.23f
#define MARG 2.0f

__global__ __launch_bounds__(256) void rga_fused(
    const float* __restrict__ pred_boxes,    // [B,L,5]
    const float* __restrict__ anchor_points, // [L,2]
    const int*   __restrict__ gt_labels,     // [B,NGT]
    const float* __restrict__ gt_boxes,      // [B,NGT,5]
    const float* __restrict__ pad_gt_mask,   // [B,NGT]
    const int*   __restrict__ bg_index_p,    // [1]
    float* __restrict__ out)
{
    // SA[n][0] = {cx, cy, ax, ay}
    // SA[n][1] = {vabx, vaby, vadx, vady}
    // SA[n][2] = {nab2, nad2, inv_dxden, inv_dyden}
    // SA[n][3] = {x1, y1, x2, y2}
    // SA[n][4] = {irp, pm1, labelf, 0}     irp = inv_refden*pad, pm1 = pad-1
    // SE[n][0] = {w, h, ang, det2}
    // SE[n][1] = {ga2, gb2, gc2, 0}
    __shared__ float4 SA[NGT][5];
    __shared__ float4 SE[NGT][2];
    __shared__ int    keep_list[NGT];
    __shared__ int    keep_cnt;

    const int b   = blockIdx.y;
    const int bx  = blockIdx.x;
    const int tid = threadIdx.x;

    // ---- per-block level geometry (all wave-uniform scalars) ----
    int Ls, sgn, log2nc;          // level start, stride, log2(cols)
    float low, high;
    if (bx < 64)      { Ls = 0;     sgn = 8;   log2nc = 7; low = -1.0f;  high = 64.0f;  }
    else if (bx < 80) { Ls = 16384; sgn = 16;  log2nc = 6; low = 64.0f;  high = 128.0f; }
    else if (bx < 84) { Ls = 20480; sgn = 32;  log2nc = 5; low = 128.0f; high = 256.0f; }
    else if (bx < 85) { Ls = 21504; sgn = 64;  log2nc = 4; low = 256.0f; high = 512.0f; }
    else              { Ls = 21760; sgn = 128; log2nc = 3; low = 512.0f; high = 1e8f;   }
    const int   nc     = 1 << log2nc;
    const int   row0   = (bx * 256 - Ls) >> log2nc;
    const int   nrows  = 256 >> log2nc;
    const int   rowlast = min(row0 + nrows, nc) - 1;
    const float fs     = (float)sgn;
    const float bymin  = (row0 + 0.5f) * fs;
    const float bymax  = (rowlast + 0.5f) * fs;
    const float bxmin  = 0.5f * fs;
    const float bxmax  = (nc - 0.5f) * fs;

    // ---- prologue: per-GT params + culling (wave 0 only) ----
    if (tid < NGT) {
        const int gi = b * NGT + tid;
        const float* g = gt_boxes + (size_t)gi * 5;
        const float cx = g[0], cy = g[1], w = g[2], h = g[3], ang = g[4];
        const float ca = cosf(ang), sa = sinf(ang);
        const float hw = 0.5f * w, hh = 0.5f * h;
        const float ax = (-hw) * ca - (-hh) * sa + cx;
        const float ay = (-hw) * sa + (-hh) * ca + cy;
        const float bx_ = ( hw) * ca - (-hh) * sa + cx;
        const float by_ = ( hw) * sa + (-hh) * ca + cy;
        const float dx_ = (-hw) * ca - ( hh) * sa + cx;
        const float dy_ = (-hw) * sa + ( hh) * ca + cy;
        const float vabx = bx_ - ax, vaby = by_ - ay;
        const float vadx = dx_ - ax, vady = dy_ - ay;
        const float nab2 = vabx * vabx + vaby * vaby;
        const float nad2 = vadx * vadx + vady * vady;
        const float norm_ab = sqrtf(nab2 + EPSV);
        const float norm_ad = sqrtf(nad2 + EPSV);
        const float min_edge = fminf(w, h);
        const float inv_dxden = 1.0f / (norm_ab * norm_ab * norm_ab * min_edge + EPSV);
        const float inv_dyden = 1.0f / (norm_ad * norm_ad * norm_ad * min_edge + EPSV);
        const float sigma = min_edge / 12.0f;
        const float inv_refden = 1.0f / (6.2831853071795864769f * sigma + EPSV);
        const float aca = fabsf(ca), asa = fabsf(sa);
        const float ew = 0.5f * (w * aca + h * asa);
        const float eh = 0.5f * (w * asa + h * aca);
        const float w2 = w * w / 12.0f, h2 = h * h / 12.0f;
        const float ga2 = w2 * ca * ca + h2 * sa * sa;
        const float gb2 = w2 * sa * sa + h2 * ca * ca;
        const float gc2 = (w2 - h2) * ca * sa;
        const float det2 = fmaxf(ga2 * gb2 - gc2 * gc2, 0.0f);
        const float pad = pad_gt_mask[gi];
        const float labelf = (float)gt_labels[gi];
        const float x1 = cx - ew, y1 = cy - eh, x2 = cx + ew, y2 = cy + eh;

        SA[tid][0] = make_float4(cx, cy, ax, ay);
        SA[tid][1] = make_float4(vabx, vaby, vadx, vady);
        SA[tid][2] = make_float4(nab2, nad2, inv_dxden, inv_dyden);
        SA[tid][3] = make_float4(x1, y1, x2, y2);
        SA[tid][4] = make_float4(inv_refden * pad, pad - 1.0f, labelf, 0.0f);
        SE[tid][0] = make_float4(w, h, ang, det2);
        SE[tid][1] = make_float4(ga2, gb2, gc2, 0.0f);

        // conservative culling: positive requires anchor inside GT AABB
        // AND ltrb_max in [low, high]; min possible ltrb_max = max(ew,eh),
        // max possible (inside AABB) = 2*max(ew,eh).
        const float me = fmaxf(ew, eh);
        const bool keep =
            (x1 <= bxmax + MARG) && (x2 >= bxmin - MARG) &&
            (y1 <= bymax + MARG) && (y2 >= bymin - MARG) &&
            (me <= high + MARG) && (2.0f * me >= low - MARG) &&
            (pad > 0.0f);
        const unsigned long long bal = __ballot(keep);
        const int lane = tid & 63;
        const int pos_i = (int)__popcll(bal & ((1ULL << lane) - 1ULL));
        if (keep) keep_list[pos_i] = tid;
        if (lane == 0) keep_cnt = (int)__popcll(bal);
    }
    __syncthreads();

    const int cnt = keep_cnt;
    const int l_raw = bx * 256 + tid;
    if (l_raw >= LTOT) return;
    const int l = l_raw;

    const float2 p = ((const float2*)anchor_points)[l];
    const float px = p.x, py = p.y;

    float best = -2.0f;
    int   bidx = 0;
    for (int i = 0; i < cnt; ++i) {
        const int n = keep_list[i];
        const float4 f0 = SA[n][0];
        const float4 f1 = SA[n][1];
        const float4 f2 = SA[n][2];
        const float4 f3 = SA[n][3];
        const float4 f4 = SA[n][4];
        const float ctpx = px - f0.x, ctpy = py - f0.y;
        const float dot_ab = ctpx * f1.x + ctpy * f1.y;
        const float dot_ad = ctpx * f1.z + ctpy * f1.w;
        const float delta = dot_ab * dot_ab * f2.z + dot_ad * dot_ad * f2.w;
        const float gauss = __expf(-6.0f * delta);
        const float apx = px - f0.z, apy = py - f0.w;
        const float ap_ab = apx * f1.x + apy * f1.y;
        const float ap_ad = apx * f1.z + apy * f1.w;
        const bool inside = (ap_ab >= EPSV) & (ap_ab <= f2.x) &
                            (ap_ad >= EPSV) & (ap_ad <= f2.y);
        const float ltrb = fmaxf(fmaxf(px - f3.x, py - f3.y),
                                 fmaxf(f3.z - px, f3.w - py));
        const bool ok = inside & (gauss > SCORE_THR) & (ltrb >= low) & (ltrb <= high);
        const float masked = ok ? fmaf(gauss, f4.x, f4.y) : -1.0f;
        if (masked > best) { best = masked; bidx = n; }
    }

    const int bg = bg_index_p[0];
    const bool pos = best > 0.0f;

    const float4 s0 = SA[bidx][0];
    const float4 s4 = SA[bidx][4];
    const float4 e0 = SE[bidx][0];
    const float4 e1 = SE[bidx][1];

    const int lbl = pos ? (int)s4.z : bg;

    const size_t idx = (size_t)b * LTOT + l;
    out[idx] = (float)lbl;

    float* outB = out + (size_t)NB * LTOT + idx * 5;
    outB[0] = pos ? s0.x : 0.0f;
    outB[1] = pos ? s0.y : 0.0f;
    outB[2] = pos ? e0.x : 0.0f;
    outB[3] = pos ? e0.y : 0.0f;
    outB[4] = pos ? e0.z : 0.0f;

    float iou = 0.0f;
    if (pos) {
        const float* pb = pred_boxes + idx * 5;
        const float pcx = pb[0], pcy = pb[1], pw = pb[2], ph = pb[3], pang = pb[4];
        const float ca = __cosf(pang), sa = __sinf(pang);
        const float w2 = pw * pw / 12.0f, h2 = ph * ph / 12.0f;
        const float a1 = w2 * ca * ca + h2 * sa * sa;
        const float b1 = w2 * sa * sa + h2 * ca * ca;
        const float c1 = (w2 - h2) * ca * sa;
        const float dx = pcx - s0.x, dy = pcy - s0.y;
        const float aa = a1 + e1.x, bb = b1 + e1.y, cc = c1 + e1.z;
        const float denom = aa * bb - cc * cc + 1e-3f;
        const float t1 = 0.25f * (aa * dy * dy + bb * dx * dx) / denom;
        const float t2 = 0.5f * (cc * (-(dx * dy))) / denom;
        const float det1 = fmaxf(a1 * b1 - c1 * c1, 0.0f);
        const float t3 = 0.5f * __logf(denom / (4.0f * __fsqrt_rn(det1 * e0.w) + 1e-3f) + 1e-3f);
        float bd = t1 + t2 + t3;
        bd = fminf(fmaxf(bd, 1e-3f), 100.0f);
        iou = 1.0f - sqrtf(1.0f - __expf(-bd) + 1e-3f);
    }

    float* outS = out + (size_t)NB * LTOT * 6 + idx * NUMC;
    #pragma unroll
    for (int c = 0; c < NUMC; ++c)
        outS[c] = (pos && c == lbl) ? iou : 0.0f;
}

extern "C" void kernel_launch(void* const* d_in, const int* in_sizes, int n_in,
                              void* d_out, int out_size, void* d_ws, size_t ws_size,
                              hipStream_t stream) {
    // inputs: 0 pred_scores (unused), 1 pred_boxes, 2 anchor_points, 3 gt_labels,
    //         4 gt_boxes, 5 pad_gt_mask, 6 bg_index, 7 stride_tensor (unused)
    const float* pred_boxes    = (const float*)d_in[1];
    const float* anchor_points = (const float*)d_in[2];
    const int*   gt_labels     = (const int*)d_in[3];
    const float* gt_boxes      = (const float*)d_in[4];
    const float* pad_gt_mask   = (const float*)d_in[5];
    const int*   bg_index_p    = (const int*)d_in[6];
    float*       out           = (float*)d_out;

    dim3 grid((LTOT + 255) / 256, NB);
    rga_fused<<<grid, dim3(256), 0, stream>>>(
        pred_boxes, anchor_points, gt_labels, gt_boxes, pad_gt_mask, bg_index_p, out);
}